// Round 4
// baseline (238.464 us; speedup 1.0000x reference)
//
#include <hip/hip_runtime.h>

#define K_CODES 1024
#define D_DIM 128
#define N_ROWS 65536
#define DECAY_F 0.99f
#define OMD_F 0.01f
#define EPS_F 1e-5f

// codes grouped in HALVES of 64 codes; hi[64][128] then lo[64][128] ushorts,
// 16B-block-swizzled: block s of code lc stored at s ^ (lc&7)  (T2, rule #21:
// linear gld16 dest + pre-swizzled global source + swizzled ds_read).
#define N_HALF 16
#define HALF_USHORT 16384              // 64*128*2
#define HALF_BYTES 32768
#define NSLOT 4                        // LDS ring: 4 * 32KB = 131072 B
#define NT 2                           // row tiles per wave; 8 waves -> 256 rows/block
#define SEG_TILE 64

// ---------------------------------------------------------------------------
// ws layout (float units). [WS_CNT, WS_ZERO_END) zeroed by ONE memset.
// ---------------------------------------------------------------------------
#define WS_CNT     0
#define WS_LOSS    1024
#define WS_BE      1028
#define WS_ZERO_END (1028 + 131072)
#define WS_ENORM   132100
#define WS_SMOOTH  133124
#define WS_CUR     134148
#define WS_FIDX    135172
#define WS_BUCKET  200708
#define WS_SCODE   266244
#define WS_EIMG    331780              // 262144 ushorts = 512 KB

typedef __bf16 bf8_t __attribute__((ext_vector_type(8)));
typedef float  f4_t  __attribute__((ext_vector_type(4)));

__device__ inline unsigned short f2bf_bits(float f) {
    __bf16 h = (__bf16)f;
    return __builtin_bit_cast(unsigned short, h);
}
__device__ inline float bf_bits2f(unsigned short u) {
    __bf16 h = __builtin_bit_cast(__bf16, u);
    return (float)h;
}

__device__ inline void gld16(const void* g, void* l) {
    __builtin_amdgcn_global_load_lds(
        (const __attribute__((address_space(1))) void*)g,
        (__attribute__((address_space(3))) void*)l, 16, 0, 0);
}

#define SBAR() do { __builtin_amdgcn_sched_barrier(0); \
                    __builtin_amdgcn_s_barrier(); \
                    __builtin_amdgcn_sched_barrier(0); } while (0)
#define SCHEDB() __builtin_amdgcn_sched_barrier(0)

// ---------------------------------------------------------------------------
// Prep: enorm + swizzled bf16 hi/lo image. 32 threads/code; grid 128 x 256.
// ---------------------------------------------------------------------------
__global__ void vq_prep(const float* __restrict__ emb, float* __restrict__ enorm,
                        unsigned short* __restrict__ eimg) {
    int t = blockIdx.x * blockDim.x + threadIdx.x;   // 32768
    int code = t >> 5;
    int q = t & 31;                                  // float4 index (8B half-block)
    float4 v = ((const float4*)(emb + (size_t)code * D_DIM))[q];
    int H = code >> 6, lc = code & 63;
    int s  = q >> 1;                                 // 16B block 0..15
    int sw = s ^ (lc & 7);                           // T2 XOR swizzle
    size_t hbase = (size_t)H * HALF_USHORT + lc * 128 + sw * 8 + (q & 1) * 4;
    size_t lbase = hbase + 8192;
    float vv[4] = {v.x, v.y, v.z, v.w};
    ushort4 hi, lo;
    unsigned short* hp = (unsigned short*)&hi;
    unsigned short* lp = (unsigned short*)&lo;
#pragma unroll
    for (int i = 0; i < 4; ++i) {
        unsigned short hb = f2bf_bits(vv[i]);
        hp[i] = hb;
        lp[i] = f2bf_bits(vv[i] - bf_bits2f(hb));
    }
    *(ushort4*)(eimg + hbase) = hi;
    *(ushort4*)(eimg + lbase) = lo;

    float s2 = v.x * v.x + v.y * v.y + v.z * v.z + v.w * v.w;
#pragma unroll
    for (int o = 1; o < 32; o <<= 1) s2 += __shfl_xor(s2, o, 64);
    if (q == 0) enorm[code] = s2;
}

// ---------------------------------------------------------------------------
__device__ inline void top2_update(float s, int code, float& s1, int& i1, float& s2, int& i2) {
    bool b1 = s < s1;
    bool b2 = s < s2;
    s2 = b1 ? s1 : (b2 ? s : s2);
    i2 = b1 ? i1 : (b2 ? code : i2);
    s1 = b1 ? s : s1;
    i1 = b1 ? code : i1;
}

__device__ inline void top2_merge(float& s1, int& i1, float& s2, int& i2,
                                  float t1, int j1, float t2, int j2) {
    bool bf = (t1 < s1) || (t1 == s1 && j1 < i1);
    float ns1 = bf ? t1 : s1;  int ni1 = bf ? j1 : i1;
    float ca  = bf ? s1 : t1;  int ia  = bf ? i1 : j1;
    float cb  = bf ? t2 : s2;  int ib  = bf ? j2 : i2;
    bool bs = (ca < cb) || (ca == cb && ia < ib);
    s1 = ns1; i1 = ni1;
    s2 = bs ? ca : cb; i2 = bs ? ia : ib;
}

// ---------------------------------------------------------------------------
// One half (64 codes) = 2 phases. Per phase: {ds_read 16 b128 | issue 2 gld16
// of half h+3 | [phase B: counted vmcnt] | bar | setprio MFMA setprio | bar |
// top2}.  8-phase-style schedule (T3+T4+T5); vmcnt never 0 in steady state.
// ---------------------------------------------------------------------------
template<int WAITN, bool STAGE>
__device__ __forceinline__ void half_body(
    int h, const char* __restrict__ eimg_b, char* ldsx, const float* lds_en,
    const bf8_t (&zh)[NT][4], const bf8_t (&zl)[NT][4],
    int wv, int lane, int l16, int quad,
    float (&s1)[NT], int (&i1)[NT], float (&s2)[NT], int (&i2)[NT])
{
    const unsigned short* buf = (const unsigned short*)(ldsx + (h & 3) * HALF_BYTES);
#pragma unroll
    for (int cg = 0; cg < 2; ++cg) {
        // ds_read this cg's fragments (swizzled addresses; ~2-way banks)
        bf8_t ah[2][4], al[2][4];
#pragma unroll
        for (int ks = 0; ks < 4; ++ks)
#pragma unroll
            for (int ct = 0; ct < 2; ++ct) {
                int lc = cg * 32 + ct * 16 + l16;
                int s  = ks * 4 + quad;
                int off = lc * 128 + ((s ^ (lc & 7)) * 8);
                ah[ct][ks] = *(const bf8_t*)&buf[off];
                al[ct][ks] = *(const bf8_t*)&buf[off + 8192];
            }
        if (STAGE) {   // issue 2 of this wave's 4 loads for half h+3
            const char* gs = eimg_b + (size_t)(h + 3) * HALF_BYTES;
            char* ls = ldsx + ((h + 3) & 3) * HALF_BYTES;
            int i0 = wv * 4 + cg * 2;
            gld16(gs + (size_t)i0 * 1024 + lane * 16, ls + i0 * 1024);
            gld16(gs + (size_t)(i0 + 1) * 1024 + lane * 16, ls + (i0 + 1) * 1024);
            SCHEDB();
        }
        if (cg == 1) {   // once per half: drain half h+1's loads only
            asm volatile("s_waitcnt vmcnt(%0)" :: "n"(WAITN) : "memory");
        }
        SBAR();
        __builtin_amdgcn_s_setprio(1);
        f4_t acc[2][NT];
#pragma unroll
        for (int ct = 0; ct < 2; ++ct)
#pragma unroll
            for (int nt = 0; nt < NT; ++nt) acc[ct][nt] = (f4_t)(0.f);
#pragma unroll
        for (int ks = 0; ks < 4; ++ks)
#pragma unroll
            for (int ct = 0; ct < 2; ++ct)
#pragma unroll
                for (int nt = 0; nt < NT; ++nt) {
                    acc[ct][nt] = __builtin_amdgcn_mfma_f32_16x16x32_bf16(
                        ah[ct][ks], zh[nt][ks], acc[ct][nt], 0, 0, 0);
                    acc[ct][nt] = __builtin_amdgcn_mfma_f32_16x16x32_bf16(
                        al[ct][ks], zh[nt][ks], acc[ct][nt], 0, 0, 0);
                    acc[ct][nt] = __builtin_amdgcn_mfma_f32_16x16x32_bf16(
                        ah[ct][ks], zl[nt][ks], acc[ct][nt], 0, 0, 0);
                }
        __builtin_amdgcn_s_setprio(0);
        SBAR();
        // top2 on this cg (VALU; runs while other waves enter next phase region)
#pragma unroll
        for (int ct = 0; ct < 2; ++ct) {
            int cb = h * 64 + cg * 32 + ct * 16 + quad * 4;
            float4 en4 = *(const float4*)&lds_en[cb];
            float env[4] = {en4.x, en4.y, en4.z, en4.w};
#pragma unroll
            for (int nt = 0; nt < NT; ++nt)
#pragma unroll
                for (int r = 0; r < 4; ++r) {
                    float sc = env[r] - 2.0f * acc[ct][nt][r];
                    top2_update(sc, cb + r, s1[nt], i1[nt], s2[nt], i2[nt]);
                }
        }
    }
}

// ---------------------------------------------------------------------------
// Fused score + decide. 512 thr = 8 waves, NT=2 -> 256 rows/block, grid 256.
// 1 block/CU; LDS = 4x32KB ring + 4KB enorm = 135168 B.
// ---------------------------------------------------------------------------
__global__ __launch_bounds__(512) void vq_score(
    const float* __restrict__ z, const unsigned short* __restrict__ eimg,
    const float* __restrict__ enorm_g, const float* __restrict__ emb,
    float* __restrict__ out_zq, float* __restrict__ out_idx,
    int* __restrict__ cnt, unsigned int* __restrict__ fidx,
    float* __restrict__ loss_acc)
{
    __shared__ __align__(16) char ldsx[NSLOT * HALF_BYTES];   // 131072 B
    __shared__ __align__(16) float lds_en[K_CODES];           // 4 KB

    const int tid  = threadIdx.x;
    const int wv   = tid >> 6;           // 0..7
    const int lane = tid & 63;
    const int l16  = lane & 15;
    const int quad = lane >> 4;
    const int rowbase = blockIdx.x * 256 + wv * 32;
    const char* eimg_b = (const char*)eimg;

    // stage all 1024 enorms once
    if (tid < 256) ((float4*)lds_en)[tid] = ((const float4*)enorm_g)[tid];

    // resident z fragments (bf16 hi/lo)
    bf8_t zh[NT][4], zl[NT][4];
#pragma unroll
    for (int nt = 0; nt < NT; ++nt) {
        int row = rowbase + nt * 16 + l16;
        const float* zr = z + (size_t)row * D_DIM;
#pragma unroll
        for (int ks = 0; ks < 4; ++ks) {
            const float4* p = (const float4*)(zr + ks * 32 + quad * 8);
            float4 a = p[0], b = p[1];
            float v[8] = {a.x, a.y, a.z, a.w, b.x, b.y, b.z, b.w};
#pragma unroll
            for (int i = 0; i < 8; ++i) {
                __bf16 hh = (__bf16)v[i];
                zh[nt][ks][i] = hh;
                zl[nt][ks][i] = (__bf16)(v[i] - (float)hh);
            }
        }
    }

    // hard-drain all prologue VMEM so vmcnt counting below is exact
    asm volatile("s_waitcnt vmcnt(0)" ::: "memory");
    SCHEDB();

    // prologue: stage halves 0,1,2 (4 gld16/wave each, FIFO order)
#pragma unroll
    for (int hh = 0; hh < 3; ++hh) {
        const char* gs = eimg_b + (size_t)hh * HALF_BYTES;
        char* ls = ldsx + hh * HALF_BYTES;
#pragma unroll
        for (int i = 0; i < 4; ++i) {
            int idx = wv * 4 + i;
            gld16(gs + (size_t)idx * 1024 + lane * 16, ls + idx * 1024);
        }
    }
    SCHEDB();

    float s1[NT], s2[NT];
    int   i1[NT], i2[NT];
#pragma unroll
    for (int nt = 0; nt < NT; ++nt) { s1[nt] = 3.4e38f; s2[nt] = 3.4e38f; i1[nt] = 0; i2[nt] = 0; }

    asm volatile("s_waitcnt vmcnt(8)" ::: "memory");   // half 0 landed; 1,2 in flight
    asm volatile("s_waitcnt lgkmcnt(0)" ::: "memory"); // enorm ds_write published
    SBAR();

    for (int h = 0; h < 13; ++h)
        half_body<8, true >(h, eimg_b, ldsx, lds_en, zh, zl, wv, lane, l16, quad, s1, i1, s2, i2);
    half_body<4, false>(13, eimg_b, ldsx, lds_en, zh, zl, wv, lane, l16, quad, s1, i1, s2, i2);
    half_body<0, false>(14, eimg_b, ldsx, lds_en, zh, zl, wv, lane, l16, quad, s1, i1, s2, i2);
    half_body<0, false>(15, eimg_b, ldsx, lds_en, zh, zl, wv, lane, l16, quad, s1, i1, s2, i2);

    // cross-quad merge (each quad saw a disjoint code subset)
#pragma unroll
    for (int off = 16; off <= 32; off <<= 1) {
#pragma unroll
        for (int nt = 0; nt < NT; ++nt) {
            float t1 = __shfl_xor(s1[nt], off, 64);
            int   j1 = __shfl_xor(i1[nt], off, 64);
            float t2 = __shfl_xor(s2[nt], off, 64);
            int   j2 = __shfl_xor(i2[nt], off, 64);
            top2_merge(s1[nt], i1[nt], s2[nt], i2[nt], t1, j1, t2, j2);
        }
    }

    // ---------------- fused decide epilogue ----------------
    float ls = 0.f;
#pragma unroll
    for (int nt = 0; nt < NT; ++nt) {
        int row = rowbase + nt * 16 + l16;
        int j1 = i1[nt], j2 = i2[nt];

        const float4* zp  = (const float4*)(z   + (size_t)row * D_DIM);
        const float4* e1p = (const float4*)(emb + (size_t)j1  * D_DIM);
        const float4* e2p = (const float4*)(emb + (size_t)j2  * D_DIM);

        float4 zv[8], a1[8], a2[8];
#pragma unroll
        for (int ks = 0; ks < 4; ++ks) {
            int o = ks * 8 + quad * 2;
            zv[ks * 2]     = zp[o];   zv[ks * 2 + 1] = zp[o + 1];
            a1[ks * 2]     = e1p[o];  a1[ks * 2 + 1] = e1p[o + 1];
            a2[ks * 2]     = e2p[o];  a2[ks * 2 + 1] = e2p[o + 1];
        }
        float p1 = 0.f, p2 = 0.f;
#pragma unroll
        for (int i = 0; i < 8; ++i) {
            p1 += zv[i].x * a1[i].x + zv[i].y * a1[i].y + zv[i].z * a1[i].z + zv[i].w * a1[i].w;
            p2 += zv[i].x * a2[i].x + zv[i].y * a2[i].y + zv[i].z * a2[i].z + zv[i].w * a2[i].w;
        }
        p1 += __shfl_xor(p1, 16, 64); p1 += __shfl_xor(p1, 32, 64);
        p2 += __shfl_xor(p2, 16, 64); p2 += __shfl_xor(p2, 32, 64);
        float sc1 = lds_en[j1] - 2.0f * p1;
        float sc2 = lds_en[j2] - 2.0f * p2;
        bool use2 = (sc2 < sc1) || (sc2 == sc1 && j2 < j1);
        int best = use2 ? j2 : j1;

        if (quad == 0) {
            out_idx[row] = (float)best;
            fidx[row] = (unsigned int)best;
            atomicAdd(cnt + best, 1);
        }

        float4* oz = (float4*)(out_zq + (size_t)row * D_DIM);
#pragma unroll
        for (int i = 0; i < 8; ++i) {
            float4 q = use2 ? a2[i] : a1[i];
            float4 zvv = zv[i];
            float4 df = {q.x - zvv.x, q.y - zvv.y, q.z - zvv.z, q.w - zvv.w};
            ls += df.x * df.x + df.y * df.y + df.z * df.z + df.w * df.w;
            float4 o = {zvv.x + df.x, zvv.y + df.y, zvv.z + df.z, zvv.w + df.w};
            oz[(i >> 1) * 8 + quad * 2 + (i & 1)] = o;
        }
    }

#pragma unroll
    for (int off = 32; off > 0; off >>= 1) ls += __shfl_down(ls, off, 64);
    if (lane == 0) atomicAdd(loss_acc, ls);
}

// ---------------------------------------------------------------------------
// scan + finalize1 fused (one launch fewer)
// ---------------------------------------------------------------------------
__global__ void vq_scan(const int* __restrict__ cnt, int* __restrict__ cursor,
                        const float* __restrict__ cs, const float* __restrict__ lacc,
                        float* __restrict__ out_ncs, float* __restrict__ out_loss,
                        float* __restrict__ smoothed)
{
    __shared__ int tmp[K_CODES];
    __shared__ float fr[16];
    int k = threadIdx.x;
    int c = cnt[k];
    tmp[k] = c;
    __syncthreads();
    for (int off = 1; off < K_CODES; off <<= 1) {
        int t = (k >= off) ? tmp[k - off] : 0;
        __syncthreads();
        tmp[k] += t;
        __syncthreads();
    }
    cursor[k] = tmp[k] - c;

    float ncs = cs[k] * DECAY_F + OMD_F * (float)c;
    out_ncs[k] = ncs;
    float s = ncs;
#pragma unroll
    for (int o = 1; o < 64; o <<= 1) s += __shfl_xor(s, o, 64);
    if ((k & 63) == 0) fr[k >> 6] = s;
    __syncthreads();
    float n = 0.f;
#pragma unroll
    for (int i = 0; i < 16; ++i) n += fr[i];
    smoothed[k] = (ncs + EPS_F) / (n + (float)K_CODES * EPS_F) * n;
    if (k == 0) out_loss[0] = lacc[0] / (float)((size_t)N_ROWS * D_DIM);
}

__global__ void vq_scatter(const unsigned int* __restrict__ fidx,
                           int* __restrict__ cursor, unsigned int* __restrict__ bucket,
                           int* __restrict__ scode)
{
    int row = blockIdx.x * blockDim.x + threadIdx.x;
    int k = (int)fidx[row];
    int slot = atomicAdd(cursor + k, 1);
    bucket[slot] = (unsigned int)row;
    scode[slot]  = k;
}

// ---------------------------------------------------------------------------
__global__ __launch_bounds__(128) void vq_segsum(
    const float* __restrict__ z, const unsigned int* __restrict__ bucket,
    const int* __restrict__ scode, float* __restrict__ be)
{
    __shared__ int sb[SEG_TILE];
    __shared__ int sc[SEG_TILE];
    const int tid = threadIdx.x;
    const int t0  = blockIdx.x * SEG_TILE;

    if (tid < SEG_TILE) sb[tid] = (int)bucket[t0 + tid];
    else if (tid < 2 * SEG_TILE) sc[tid - SEG_TILE] = scode[t0 + tid - SEG_TILE];
    __syncthreads();

    const int d = tid;
    float acc = 0.f;
    int cur = sc[0];

    for (int i = 0; i < SEG_TILE; i += 8) {
        float v[8];
#pragma unroll
        for (int j = 0; j < 8; ++j)
            v[j] = z[(size_t)sb[i + j] * D_DIM + d];
#pragma unroll
        for (int j = 0; j < 8; ++j) {
            int c = sc[i + j];
            if (c != cur) {
                atomicAdd(be + (size_t)cur * D_DIM + d, acc);
                acc = 0.f;
                cur = c;
            }
            acc += v[j];
        }
    }
    atomicAdd(be + (size_t)cur * D_DIM + d, acc);
}

__global__ void vq_finalize2(const float* __restrict__ ema_w, const float* __restrict__ be,
                             const float* __restrict__ smoothed,
                             float* __restrict__ out_emb, float* __restrict__ out_ema)
{
    int i = blockIdx.x * blockDim.x + threadIdx.x;
    float e = ema_w[i] * DECAY_F + OMD_F * be[i];
    out_ema[i] = e;
    out_emb[i] = e / smoothed[i >> 7];
}

// ---------------------------------------------------------------------------
extern "C" void kernel_launch(void* const* d_in, const int* in_sizes, int n_in,
                              void* d_out, int out_size, void* d_ws, size_t ws_size,
                              hipStream_t stream) {
    const float* z   = (const float*)d_in[0];
    const float* emb = (const float*)d_in[1];
    const float* cs  = (const float*)d_in[2];
    const float* ema = (const float*)d_in[3];

    float* out    = (float*)d_out;
    float* o_zq   = out;
    float* o_idx  = o_zq + (size_t)N_ROWS * D_DIM;
    float* o_loss = o_idx + N_ROWS;
    float* o_emb  = o_loss + 1;
    float* o_ncs  = o_emb + K_CODES * D_DIM;
    float* o_ema  = o_ncs + K_CODES;

    float* ws = (float*)d_ws;
    int*            cnt      = (int*)(ws + WS_CNT);
    float*          lacc     = ws + WS_LOSS;
    float*          be       = ws + WS_BE;
    float*          enorm    = ws + WS_ENORM;
    float*          smoothed = ws + WS_SMOOTH;
    int*            cursor   = (int*)(ws + WS_CUR);
    unsigned int*   fidx     = (unsigned int*)(ws + WS_FIDX);
    unsigned int*   bucket   = (unsigned int*)(ws + WS_BUCKET);
    int*            scode    = (int*)(ws + WS_SCODE);
    unsigned short* eimg     = (unsigned short*)(ws + WS_EIMG);

    hipMemsetAsync(ws, 0, (size_t)WS_ZERO_END * sizeof(float), stream);
    vq_prep<<<128, 256, 0, stream>>>(emb, enorm, eimg);
    vq_score<<<256, 512, 0, stream>>>(z, eimg, enorm, emb,
                                      o_zq, o_idx, cnt, fidx, lacc);
    vq_scan<<<1, K_CODES, 0, stream>>>(cnt, cursor, cs, lacc, o_ncs, o_loss, smoothed);
    vq_scatter<<<N_ROWS / 256, 256, 0, stream>>>(fidx, cursor, bucket, scode);
    vq_segsum<<<N_ROWS / SEG_TILE, 128, 0, stream>>>(z, bucket, scode, be);
    vq_finalize2<<<K_CODES * D_DIM / 256, 256, 0, stream>>>(ema, be, smoothed, o_emb, o_ema);
}

// Round 5
// 212.530 us; speedup vs baseline: 1.1220x; 1.1220x over previous
//
#include <hip/hip_runtime.h>

#define K_CODES 1024
#define D_DIM 128
#define N_ROWS 65536
#define DECAY_F 0.99f
#define OMD_F 0.01f
#define EPS_F 1e-5f

#define EPAD 144                       // padded bf16 row: 288 B; conflict-free (R1-proven)
#define CHUNK_CODES 64
#define N_CHUNKS 16
#define CHUNK_USHORT (2 * CHUNK_CODES * EPAD)   // 18432 ushorts = 36864 B
#define NT 2                           // row tiles per wave (128 rows/block, grid 512)
#define SEG_TILE 128

// ---------------------------------------------------------------------------
// ws layout (float units). NO memset: prep zeroes [WS_CNT, WS_ZERO_END).
//   cnt[1024] int | loss[1] | pad[3] | be[131072] | enorm | smoothed | cursor
//   packed u64[65536] at WS_BUCKET (spans old bucket+scode) | eimg
// ---------------------------------------------------------------------------
#define WS_CNT     0
#define WS_LOSS    1024
#define WS_BE      1028
#define WS_ZERO_END (1028 + 131072)
#define WS_ENORM   132100
#define WS_SMOOTH  133124
#define WS_CUR     134148
#define WS_FIDX    135172
#define WS_BUCKET  200708              // u64[65536]; byte off %8 == 0
#define WS_EIMG    331780              // byte off 1327120, 16B aligned

typedef __bf16 bf8_t __attribute__((ext_vector_type(8)));
typedef float  f4_t  __attribute__((ext_vector_type(4)));

__device__ inline unsigned short f2bf_bits(float f) {
    __bf16 h = (__bf16)f;
    return __builtin_bit_cast(unsigned short, h);
}
__device__ inline float bf_bits2f(unsigned short u) {
    __bf16 h = __builtin_bit_cast(__bf16, u);
    return (float)h;
}

// async global->LDS, 16 B per lane. lds dest is wave-uniform base (+lane*16 in HW).
__device__ inline void gld16(const void* g, void* l) {
    __builtin_amdgcn_global_load_lds(
        (const __attribute__((address_space(1))) void*)g,
        (__attribute__((address_space(3))) void*)l, 16, 0, 0);
}

// ---------------------------------------------------------------------------
// Prep: enorm + bf16 hi/lo split image, one pass over emb.
// Also zeroes cnt/loss/be (replaces the hipMemsetAsync launch).
// 32 threads per code; grid 128 x 256.
// ---------------------------------------------------------------------------
__global__ void vq_prep(const float* __restrict__ emb, float* __restrict__ enorm,
                        unsigned short* __restrict__ eimg,
                        float4* __restrict__ zero_head, float4* __restrict__ zero_be) {
    int t = blockIdx.x * blockDim.x + threadIdx.x;   // 32768
    // zero accumulators: head = cnt[1024]+loss[1]+pad[3] = 257 float4; be = 32768 float4
    float4 z4 = {0.f, 0.f, 0.f, 0.f};
    if (t < 257) zero_head[t] = z4;
    zero_be[t] = z4;

    int code = t >> 5;
    int q = t & 31;
    float4 v = ((const float4*)(emb + (size_t)code * D_DIM))[q];
    int chunk = code >> 6, c = code & 63;
    size_t hbase = (size_t)chunk * CHUNK_USHORT + (size_t)c * EPAD + q * 4;
    size_t lbase = hbase + (size_t)CHUNK_CODES * EPAD;
    float vv[4] = {v.x, v.y, v.z, v.w};
    ushort4 hi, lo;
    unsigned short* hp = (unsigned short*)&hi;
    unsigned short* lp = (unsigned short*)&lo;
#pragma unroll
    for (int i = 0; i < 4; ++i) {
        unsigned short hb = f2bf_bits(vv[i]);
        hp[i] = hb;
        lp[i] = f2bf_bits(vv[i] - bf_bits2f(hb));
    }
    *(ushort4*)(eimg + hbase) = hi;
    *(ushort4*)(eimg + lbase) = lo;

    float s = v.x * v.x + v.y * v.y + v.z * v.z + v.w * v.w;
#pragma unroll
    for (int o = 1; o < 32; o <<= 1) s += __shfl_xor(s, o, 64);
    if (q == 0) enorm[code] = s;
}

// ---------------------------------------------------------------------------
__device__ inline void top2_update(float s, int code, float& s1, int& i1, float& s2, int& i2) {
    bool b1 = s < s1;
    bool b2 = s < s2;
    s2 = b1 ? s1 : (b2 ? s : s2);
    i2 = b1 ? i1 : (b2 ? code : i2);
    s1 = b1 ? s : s1;
    i1 = b1 ? code : i1;
}

__device__ inline void top2_merge(float& s1, int& i1, float& s2, int& i2,
                                  float t1, int j1, float t2, int j2) {
    bool bf = (t1 < s1) || (t1 == s1 && j1 < i1);
    float ns1 = bf ? t1 : s1;  int ni1 = bf ? j1 : i1;
    float ca  = bf ? s1 : t1;  int ia  = bf ? i1 : j1;
    float cb  = bf ? t2 : s2;  int ib  = bf ? j2 : i2;
    bool bs = (ca < cb) || (ca == cb && ia < ib);
    s1 = ns1; i1 = ni1;
    s2 = bs ? ca : cb; i2 = bs ? ia : ib;
}

// ---------------------------------------------------------------------------
// Fused score + decide. Block: 256 thr = 4 waves, nt=2 -> 128 rows/block.
// Grid 512 (2 blocks/CU: proven best config, 90 us). BYTE-IDENTICAL to R1.
// ---------------------------------------------------------------------------
__global__ __launch_bounds__(256) void vq_score(
    const float* __restrict__ z, const unsigned short* __restrict__ eimg,
    const float* __restrict__ enorm_g, const float* __restrict__ emb,
    float* __restrict__ out_zq, float* __restrict__ out_idx,
    int* __restrict__ cnt, unsigned int* __restrict__ fidx,
    float* __restrict__ loss_acc)
{
    __shared__ __align__(16) unsigned short lds[2][CHUNK_USHORT];  // 73728 B
    __shared__ __align__(16) float lds_en[K_CODES];                // 4 KB

    const int tid  = threadIdx.x;
    const int wv   = tid >> 6;
    const int lane = tid & 63;
    const int l16  = lane & 15;
    const int quad = lane >> 4;
    const int rowbase = blockIdx.x * 128 + wv * 32;

    // stage all 1024 enorms once
    ((float4*)lds_en)[tid] = ((const float4*)enorm_g)[tid];

    // async-stage chunk 0 into buf 0 (9 x 1KB per wave)
    {
        const char* gs = (const char*)eimg;
        char* ls = (char*)&lds[0][0];
        int wb = wv * 9216;
#pragma unroll
        for (int i = 0; i < 9; ++i)
            gld16(gs + wb + i * 1024 + lane * 16, ls + wb + i * 1024);
    }

    // resident z fragments (bf16 hi/lo), rows = rowbase + nt*16 + l16
    bf8_t zh[NT][4], zl[NT][4];
#pragma unroll
    for (int nt = 0; nt < NT; ++nt) {
        int row = rowbase + nt * 16 + l16;
        const float* zr = z + (size_t)row * D_DIM;
#pragma unroll
        for (int ks = 0; ks < 4; ++ks) {
            const float4* p = (const float4*)(zr + ks * 32 + quad * 8);
            float4 a = p[0], b = p[1];
            float v[8] = {a.x, a.y, a.z, a.w, b.x, b.y, b.z, b.w};
#pragma unroll
            for (int i = 0; i < 8; ++i) {
                __bf16 hh = (__bf16)v[i];
                zh[nt][ks][i] = hh;
                zl[nt][ks][i] = (__bf16)(v[i] - (float)hh);
            }
        }
    }

    float s1[NT], s2[NT];
    int   i1[NT], i2[NT];
#pragma unroll
    for (int nt = 0; nt < NT; ++nt) { s1[nt] = 3.4e38f; s2[nt] = 3.4e38f; i1[nt] = 0; i2[nt] = 0; }

    __syncthreads();   // drains chunk-0 async loads (vmcnt 0 before barrier)

    for (int c = 0; c < N_CHUNKS; ++c) {
        const int cur = c & 1;
        if (c + 1 < N_CHUNKS) {   // prefetch next chunk into other buffer
            const char* gs = (const char*)(eimg + (size_t)(c + 1) * CHUNK_USHORT);
            char* ls = (char*)&lds[1 - cur][0];
            int wb = wv * 9216;
#pragma unroll
            for (int i = 0; i < 9; ++i)
                gld16(gs + wb + i * 1024 + lane * 16, ls + wb + i * 1024);
        }
        const unsigned short* buf = &lds[cur][0];

#pragma unroll
        for (int cg = 0; cg < 2; ++cg) {     // 32 codes per pass
            f4_t acc[2][NT];
#pragma unroll
            for (int ct = 0; ct < 2; ++ct)
#pragma unroll
                for (int nt = 0; nt < NT; ++nt) acc[ct][nt] = (f4_t)(0.f);

#pragma unroll
            for (int ks = 0; ks < 4; ++ks) {
                bf8_t ah[2], al[2];
#pragma unroll
                for (int ct = 0; ct < 2; ++ct) {
                    int cl = cg * 32 + ct * 16 + l16;
                    int base = cl * EPAD + ks * 32 + quad * 8;
                    ah[ct] = *(const bf8_t*)&buf[base];
                    al[ct] = *(const bf8_t*)&buf[CHUNK_CODES * EPAD + base];
                }
#pragma unroll
                for (int ct = 0; ct < 2; ++ct)
#pragma unroll
                    for (int nt = 0; nt < NT; ++nt) {
                        acc[ct][nt] = __builtin_amdgcn_mfma_f32_16x16x32_bf16(
                            ah[ct], zh[nt][ks], acc[ct][nt], 0, 0, 0);
                        acc[ct][nt] = __builtin_amdgcn_mfma_f32_16x16x32_bf16(
                            al[ct], zh[nt][ks], acc[ct][nt], 0, 0, 0);
                        acc[ct][nt] = __builtin_amdgcn_mfma_f32_16x16x32_bf16(
                            ah[ct], zl[nt][ks], acc[ct][nt], 0, 0, 0);
                    }
            }

#pragma unroll
            for (int ct = 0; ct < 2; ++ct) {
                int cb = c * 64 + cg * 32 + ct * 16 + quad * 4;
                float4 en4 = *(const float4*)&lds_en[cb];
                float env[4] = {en4.x, en4.y, en4.z, en4.w};
#pragma unroll
                for (int nt = 0; nt < NT; ++nt)
#pragma unroll
                    for (int r = 0; r < 4; ++r) {
                        float s = env[r] - 2.0f * acc[ct][nt][r];
                        top2_update(s, cb + r, s1[nt], i1[nt], s2[nt], i2[nt]);
                    }
            }
        }
        __syncthreads();   // all waves done with buf[cur]; prefetch drained
    }

    // cross-quad merge (each quad saw a disjoint code subset)
#pragma unroll
    for (int off = 16; off <= 32; off <<= 1) {
#pragma unroll
        for (int nt = 0; nt < NT; ++nt) {
            float t1 = __shfl_xor(s1[nt], off, 64);
            int   j1 = __shfl_xor(i1[nt], off, 64);
            float t2 = __shfl_xor(s2[nt], off, 64);
            int   j2 = __shfl_xor(i2[nt], off, 64);
            top2_merge(s1[nt], i1[nt], s2[nt], i2[nt], t1, j1, t2, j2);
        }
    }

    // ---------------- fused decide epilogue ----------------
    float ls = 0.f;
#pragma unroll
    for (int nt = 0; nt < NT; ++nt) {
        int row = rowbase + nt * 16 + l16;
        int j1 = i1[nt], j2 = i2[nt];      // uniform across the row's 4 quad-lanes

        const float4* zp  = (const float4*)(z   + (size_t)row * D_DIM);
        const float4* e1p = (const float4*)(emb + (size_t)j1  * D_DIM);
        const float4* e2p = (const float4*)(emb + (size_t)j2  * D_DIM);

        float4 zv[8], a1[8], a2[8];
#pragma unroll
        for (int ks = 0; ks < 4; ++ks) {
            int o = ks * 8 + quad * 2;
            zv[ks * 2]     = zp[o];   zv[ks * 2 + 1] = zp[o + 1];
            a1[ks * 2]     = e1p[o];  a1[ks * 2 + 1] = e1p[o + 1];
            a2[ks * 2]     = e2p[o];  a2[ks * 2 + 1] = e2p[o + 1];
        }
        float p1 = 0.f, p2 = 0.f;
#pragma unroll
        for (int i = 0; i < 8; ++i) {
            p1 += zv[i].x * a1[i].x + zv[i].y * a1[i].y + zv[i].z * a1[i].z + zv[i].w * a1[i].w;
            p2 += zv[i].x * a2[i].x + zv[i].y * a2[i].y + zv[i].z * a2[i].z + zv[i].w * a2[i].w;
        }
        p1 += __shfl_xor(p1, 16, 64); p1 += __shfl_xor(p1, 32, 64);
        p2 += __shfl_xor(p2, 16, 64); p2 += __shfl_xor(p2, 32, 64);
        float sc1 = lds_en[j1] - 2.0f * p1;
        float sc2 = lds_en[j2] - 2.0f * p2;
        bool use2 = (sc2 < sc1) || (sc2 == sc1 && j2 < j1);
        int best = use2 ? j2 : j1;

        if (quad == 0) {
            out_idx[row] = (float)best;
            fidx[row] = (unsigned int)best;
            atomicAdd(cnt + best, 1);
        }

        float4* oz = (float4*)(out_zq + (size_t)row * D_DIM);
#pragma unroll
        for (int i = 0; i < 8; ++i) {
            float4 q = use2 ? a2[i] : a1[i];
            float4 zvv = zv[i];
            float4 df = {q.x - zvv.x, q.y - zvv.y, q.z - zvv.z, q.w - zvv.w};
            ls += df.x * df.x + df.y * df.y + df.z * df.z + df.w * df.w;
            float4 o = {zvv.x + df.x, zvv.y + df.y, zvv.z + df.z, zvv.w + df.w};
            oz[(i >> 1) * 8 + quad * 2 + (i & 1)] = o;
        }
    }

#pragma unroll
    for (int off = 32; off > 0; off >>= 1) ls += __shfl_down(ls, off, 64);
    if (lane == 0) atomicAdd(loss_acc, ls);
}

// ---------------------------------------------------------------------------
// Scan (shfl-based, 1 barrier) + finalize1 fused.
// ---------------------------------------------------------------------------
__global__ void vq_scan(const int* __restrict__ cnt, int* __restrict__ cursor,
                        const float* __restrict__ cs, const float* __restrict__ lacc,
                        float* __restrict__ out_ncs, float* __restrict__ out_loss,
                        float* __restrict__ smoothed)
{
    __shared__ int   wsum[16];
    __shared__ float fr[16];
    int k = threadIdx.x;
    int wv = k >> 6, lane = k & 63;
    int c = cnt[k];

    // inclusive wave scan of c
    int x = c;
#pragma unroll
    for (int off = 1; off < 64; off <<= 1) {
        int t = __shfl_up(x, off, 64);
        if (lane >= off) x += t;
    }
    if (lane == 63) wsum[wv] = x;

    float ncs = cs[k] * DECAY_F + OMD_F * (float)c;
    out_ncs[k] = ncs;
    float s = ncs;
#pragma unroll
    for (int o = 1; o < 64; o <<= 1) s += __shfl_xor(s, o, 64);
    if (lane == 0) fr[wv] = s;
    __syncthreads();

    int woff = 0; float n = 0.f;
#pragma unroll
    for (int i = 0; i < 16; ++i) {
        if (i < wv) woff += wsum[i];
        n += fr[i];
    }
    cursor[k] = woff + x - c;           // exclusive prefix sum
    smoothed[k] = (ncs + EPS_F) / (n + (float)K_CODES * EPS_F) * n;
    if (k == 0) out_loss[0] = lacc[0] / (float)((size_t)N_ROWS * D_DIM);
}

// ---------------------------------------------------------------------------
// Scatter: one packed 8B write per row (code<<32 | row) instead of 2x4B.
// ---------------------------------------------------------------------------
__global__ void vq_scatter(const unsigned int* __restrict__ fidx,
                           int* __restrict__ cursor,
                           unsigned long long* __restrict__ packed)
{
    int row = blockIdx.x * blockDim.x + threadIdx.x;
    int k = (int)fidx[row];
    int slot = atomicAdd(cursor + k, 1);
    packed[slot] = ((unsigned long long)(unsigned)k << 32) | (unsigned)row;
}

// ---------------------------------------------------------------------------
// Skew-oblivious segment sum over code-sorted slots; 128-slot tiles, grid 512.
// ---------------------------------------------------------------------------
__global__ __launch_bounds__(128) void vq_segsum(
    const float* __restrict__ z, const unsigned long long* __restrict__ packed,
    float* __restrict__ be)
{
    __shared__ int sb[SEG_TILE];
    __shared__ int sc[SEG_TILE];
    const int tid = threadIdx.x;
    const int t0  = blockIdx.x * SEG_TILE;

    {
        unsigned long long v = packed[t0 + tid];
        sb[tid] = (int)(unsigned)(v & 0xffffffffu);
        sc[tid] = (int)(v >> 32);
    }
    __syncthreads();

    const int d = tid;
    float acc = 0.f;
    int cur = sc[0];

    for (int i = 0; i < SEG_TILE; i += 8) {
        float v[8];
#pragma unroll
        for (int j = 0; j < 8; ++j)
            v[j] = z[(size_t)sb[i + j] * D_DIM + d];
#pragma unroll
        for (int j = 0; j < 8; ++j) {
            int c = sc[i + j];
            if (c != cur) {
                atomicAdd(be + (size_t)cur * D_DIM + d, acc);
                acc = 0.f;
                cur = c;
            }
            acc += v[j];
        }
    }
    atomicAdd(be + (size_t)cur * D_DIM + d, acc);
}

// ---------------------------------------------------------------------------
__global__ void vq_finalize2(const float* __restrict__ ema_w, const float* __restrict__ be,
                             const float* __restrict__ smoothed,
                             float* __restrict__ out_emb, float* __restrict__ out_ema)
{
    int i = blockIdx.x * blockDim.x + threadIdx.x;
    float e = ema_w[i] * DECAY_F + OMD_F * be[i];
    out_ema[i] = e;
    out_emb[i] = e / smoothed[i >> 7];
}

// ---------------------------------------------------------------------------
extern "C" void kernel_launch(void* const* d_in, const int* in_sizes, int n_in,
                              void* d_out, int out_size, void* d_ws, size_t ws_size,
                              hipStream_t stream) {
    const float* z   = (const float*)d_in[0];
    const float* emb = (const float*)d_in[1];
    const float* cs  = (const float*)d_in[2];
    const float* ema = (const float*)d_in[3];

    float* out    = (float*)d_out;
    float* o_zq   = out;
    float* o_idx  = o_zq + (size_t)N_ROWS * D_DIM;
    float* o_loss = o_idx + N_ROWS;
    float* o_emb  = o_loss + 1;
    float* o_ncs  = o_emb + K_CODES * D_DIM;
    float* o_ema  = o_ncs + K_CODES;

    float* ws = (float*)d_ws;
    int*                 cnt      = (int*)(ws + WS_CNT);
    float*               lacc     = ws + WS_LOSS;
    float*               be       = ws + WS_BE;
    float*               enorm    = ws + WS_ENORM;
    float*               smoothed = ws + WS_SMOOTH;
    int*                 cursor   = (int*)(ws + WS_CUR);
    unsigned int*        fidx     = (unsigned int*)(ws + WS_FIDX);
    unsigned long long*  packed   = (unsigned long long*)(ws + WS_BUCKET);
    unsigned short*      eimg     = (unsigned short*)(ws + WS_EIMG);

    vq_prep<<<128, 256, 0, stream>>>(emb, enorm, eimg,
                                     (float4*)(ws + WS_CNT), (float4*)(ws + WS_BE));
    vq_score<<<512, 256, 0, stream>>>(z, eimg, enorm, emb,
                                      o_zq, o_idx, cnt, fidx, lacc);
    vq_scan<<<1, K_CODES, 0, stream>>>(cnt, cursor, cs, lacc, o_ncs, o_loss, smoothed);
    vq_scatter<<<N_ROWS / 256, 256, 0, stream>>>(fidx, cursor, packed);
    vq_segsum<<<N_ROWS / SEG_TILE, 128, 0, stream>>>(z, packed, be);
    vq_finalize2<<<K_CODES * D_DIM / 256, 256, 0, stream>>>(ema, be, smoothed, o_emb, o_ema);
}